// Round 1
// baseline (5182.454 us; speedup 1.0000x reference)
//
#include <hip/hip_runtime.h>
#include <cstdint>

#define BATCH 64
#define NODES 207
#define HID   64
#define NH    (NODES*HID)      // 13248
#define TOT   (BATCH*NH)       // 847872
#define NSTEPS 100

// ---------------- threefry2x32 (JAX semantics) ----------------
__device__ __forceinline__ uint32_t rotl32(uint32_t v, int n) {
    return (v << n) | (v >> (32 - n));
}

__device__ __forceinline__ void threefry2x32(uint32_t k0, uint32_t k1,
                                             uint32_t& x0, uint32_t& x1) {
    uint32_t ks0 = k0, ks1 = k1, ks2 = k0 ^ k1 ^ 0x1BD11BDAu;
    x0 += ks0; x1 += ks1;
#define TF_ROUND(r) { x0 += x1; x1 = rotl32(x1, (r)); x1 ^= x0; }
    TF_ROUND(13) TF_ROUND(15) TF_ROUND(26) TF_ROUND(6)
    x0 += ks1; x1 += ks2 + 1u;
    TF_ROUND(17) TF_ROUND(29) TF_ROUND(16) TF_ROUND(24)
    x0 += ks2; x1 += ks0 + 2u;
    TF_ROUND(13) TF_ROUND(15) TF_ROUND(26) TF_ROUND(6)
    x0 += ks0; x1 += ks1 + 3u;
    TF_ROUND(17) TF_ROUND(29) TF_ROUND(16) TF_ROUND(24)
    x0 += ks1; x1 += ks2 + 4u;
    TF_ROUND(13) TF_ROUND(15) TF_ROUND(26) TF_ROUND(6)
    x0 += ks2; x1 += ks0 + 5u;
#undef TF_ROUND
}

// ---------------- erfinv (XLA f32 path, Giles) ----------------
__device__ __forceinline__ float erfinv32(float x) {
    float w = -log1pf(-x * x);
    float p;
    if (w < 5.0f) {
        w = w - 2.5f;
        p =             2.81022636e-08f;
        p = fmaf(p, w,  3.43273939e-07f);
        p = fmaf(p, w, -3.5233877e-06f);
        p = fmaf(p, w, -4.39150654e-06f);
        p = fmaf(p, w,  0.00021858087f);
        p = fmaf(p, w, -0.00125372503f);
        p = fmaf(p, w, -0.00417768164f);
        p = fmaf(p, w,  0.246640727f);
        p = fmaf(p, w,  1.50140941f);
    } else {
        w = sqrtf(w) - 3.0f;
        p =            -0.000200214257f;
        p = fmaf(p, w,  0.000100950558f);
        p = fmaf(p, w,  0.00134934322f);
        p = fmaf(p, w, -0.00367342844f);
        p = fmaf(p, w,  0.00573950773f);
        p = fmaf(p, w, -0.0076224613f);
        p = fmaf(p, w,  0.00943887047f);
        p = fmaf(p, w,  1.00167406f);
        p = fmaf(p, w,  2.83297682f);
    }
    return p * x;
}

// bits -> N(0,1) matching jax.random.normal f32 path
__device__ __forceinline__ float bits_to_normal(uint32_t bits) {
    uint32_t fb = (bits >> 9) | 0x3f800000u;
    float f = __uint_as_float(fb) - 1.0f;   // [0,1)
    const float lo = -0.99999994f;          // nextafter(-1,0)
    float u = f * 2.0f + lo;                // (maxval-minval) rounds to 2.0f
    u = fmaxf(lo, u);
    return 1.41421356237f * erfinv32(u);    // sqrt(2) f32
}

// ---------------- kernels ----------------

// y <- x copy, and derive the 100 step keys:
// partitionable split: key_s = threefry2x32((0,42), hi=0, lo=s)
__global__ void k_init(const float* __restrict__ x, float* __restrict__ y,
                       uint32_t* __restrict__ keys) {
    int tid = blockIdx.x * blockDim.x + threadIdx.x;
    int n4 = TOT / 4;
    int stride = gridDim.x * blockDim.x;
    for (int i = tid; i < n4; i += stride) {
        ((float4*)y)[i] = ((const float4*)x)[i];
    }
    if (tid < NSTEPS) {
        uint32_t x0 = 0u, x1 = (uint32_t)tid;
        threefry2x32(0u, 42u, x0, x1);
        keys[2*tid]   = x0;
        keys[2*tid+1] = x1;
    }
}

// AY[b,m,h] = sum_n A[m,n] * y[b,n,h]; y[b] staged in LDS (53 KB)
#define MT 32
__global__ __launch_bounds__(256) void k_ay(const float* __restrict__ A,
                                            const float* __restrict__ y,
                                            float* __restrict__ ay) {
    __shared__ float Ylds[NH];          // 13248 floats = 52.99 KB
    int b  = blockIdx.x;                // 0..63
    int mt = blockIdx.y;                // 0..6
    const float* yb = y + (size_t)b * NH;
    for (int i = threadIdx.x; i < NH/4; i += 256) {
        ((float4*)Ylds)[i] = ((const float4*)yb)[i];
    }
    __syncthreads();
    int h   = threadIdx.x & 63;
    int mi0 = threadIdx.x >> 6;         // wave id: each wave = one m row at a time
    int m0  = mt * MT;
    for (int mi = mi0; mi < MT; mi += 4) {
        int m = m0 + mi;
        if (m < NODES) {
            const float* Arow = A + (size_t)m * NODES;
            float acc = 0.0f;
            for (int n = 0; n < NODES; ++n) {
                acc = fmaf(Arow[n], Ylds[n*64 + h], acc);   // Arow[n] wave-uniform
            }
            ay[((size_t)b*NODES + m)*64 + h] = acc;
        }
    }
}

// per row: T = tanh(AYrow@Wt + bt), D = tanh(AYrow@Wd + bd)
// y += 0.1*T*dt + 0.1*D*(sqrt_dt*normal)
__global__ __launch_bounds__(256) void k_step(const float* __restrict__ ay,
                                              float* __restrict__ y,
                                              const float* __restrict__ Wt,
                                              const float* __restrict__ bt,
                                              const float* __restrict__ Wd,
                                              const float* __restrict__ bd,
                                              const uint32_t* __restrict__ keys,
                                              int s) {
    __shared__ float R[4][64];
    int r = threadIdx.x >> 6;
    int h = threadIdx.x & 63;
    int row = blockIdx.x * 4 + r;       // 13248/4 = 3312 blocks exactly
    R[r][h] = ay[(size_t)row*64 + h];
    __syncthreads();
    float accT = 0.f, accD = 0.f;
#pragma unroll 8
    for (int k = 0; k < 64; ++k) {
        float a = R[r][k];              // LDS broadcast within wave
        accT = fmaf(a, Wt[k*64 + h], accT);
        accD = fmaf(a, Wd[k*64 + h], accD);
    }
    float F = 0.1f * tanhf(accT + bt[h]);
    float G = 0.1f * tanhf(accD + bd[h]);
    uint32_t j = (uint32_t)(row*64 + h);     // flat index into (64,13248) noise array
    uint32_t x0 = 0u, x1 = j;
    threefry2x32(keys[2*s], keys[2*s+1], x0, x1);
    float nrm = bits_to_normal(x0 ^ x1);     // partitionable: out0 ^ out1
    float dW  = 0.1f * nrm;                  // sqrt(0.01f) == 0.1f in f32
    size_t idx = (size_t)row*64 + h;
    y[idx] = (y[idx] + F * 0.01f) + G * dW;
}

// out[row, col] = tanh(sum_h y[row,h]*Wo[h,col] + bo[col]); row<13248, col<4096
__global__ __launch_bounds__(256) void k_out(const float* __restrict__ y,
                                             const float* __restrict__ Wo,
                                             const float* __restrict__ bo,
                                             float* __restrict__ out) {
    __shared__ float Y[16*64];          // 4 KB
    int r0  = blockIdx.x * 16;          // 828 tiles
    int c0  = blockIdx.y * 256;         // 16 tiles
    ((float4*)Y)[threadIdx.x] = ((const float4*)(y + (size_t)r0*64))[threadIdx.x];
    __syncthreads();
    int col = c0 + threadIdx.x;
    float acc[16];
#pragma unroll
    for (int r = 0; r < 16; ++r) acc[r] = 0.f;
    for (int k = 0; k < 64; ++k) {
        float w = Wo[(size_t)k*4096 + col];
#pragma unroll
        for (int r = 0; r < 16; ++r)
            acc[r] = fmaf(Y[r*64 + k], w, acc[r]);
    }
    float bb = bo[col];
#pragma unroll
    for (int r = 0; r < 16; ++r)
        out[(size_t)(r0 + r)*4096 + col] = tanhf(acc[r] + bb);
}

extern "C" void kernel_launch(void* const* d_in, const int* in_sizes, int n_in,
                              void* d_out, int out_size, void* d_ws, size_t ws_size,
                              hipStream_t stream) {
    const float* x  = (const float*)d_in[0];
    const float* A  = (const float*)d_in[1];
    const float* Wt = (const float*)d_in[2];
    const float* bt = (const float*)d_in[3];
    const float* Wd = (const float*)d_in[4];
    const float* bd = (const float*)d_in[5];
    const float* Wo = (const float*)d_in[6];
    const float* bo = (const float*)d_in[7];
    float* out = (float*)d_out;

    float* y  = (float*)d_ws;                 // 3.39 MB
    float* ay = y + TOT;                      // 3.39 MB
    uint32_t* keys = (uint32_t*)(ay + TOT);   // 800 B

    k_init<<<512, 256, 0, stream>>>(x, y, keys);
    for (int s = 0; s < NSTEPS; ++s) {
        k_ay  <<<dim3(BATCH, (NODES + MT - 1)/MT), 256, 0, stream>>>(A, y, ay);
        k_step<<<TOT/(4*64), 256, 0, stream>>>(ay, y, Wt, bt, Wd, bd, keys, s);
    }
    k_out<<<dim3(13248/16, 4096/256), 256, 0, stream>>>(y, Wo, bo, out);
}